// Round 16
// baseline (212.918 us; speedup 1.0000x reference)
//
#include <hip/hip_runtime.h>

#define S_LEN 4096
#define NH 12
#define HD 64
#define DMODEL 768
#define BATCH 2
#define MTOT (BATCH * S_LEN) /* 8192 */

typedef __bf16 bf16x8 __attribute__((ext_vector_type(8)));
typedef __bf16 bf16x4 __attribute__((ext_vector_type(4)));
typedef float f32x4 __attribute__((ext_vector_type(4)));
typedef float f32x8 __attribute__((ext_vector_type(8)));

#define SM_SCALE_LOG2E 0.18033688f /* 0.125 * log2(e), folded into Q at GEMM1 */
#define SLAB_STRIDE 16896          /* 128x64 bf16 O (16384) + 128 f32 rowsum (512) */

__device__ __forceinline__ f32x4 f32x4_zero() {
  f32x4 z = {0.f, 0.f, 0.f, 0.f};
  return z;
}

// async global->LDS DMA, 16B per lane. LDS dest = wave-uniform base + lane*16
// (linear); swizzled layouts realized by pre-swizzling the per-lane GLOBAL
// source address (rule #21). Drained by the vmcnt(0) before s_barrier.
__device__ __forceinline__ void async16(const __bf16* g, void* l) {
  __builtin_amdgcn_global_load_lds(
      (const __attribute__((address_space(1))) void*)g,
      (__attribute__((address_space(3))) void*)l, 16, 0, 0);
}

// ---------------- prep: f32 -> bf16 (vectorized) ----------------
__global__ __launch_bounds__(256) void cvt_f32_bf16(const float* __restrict__ in,
                                                    __bf16* __restrict__ out, int n8) {
  int i = blockIdx.x * 256 + threadIdx.x;
  if (i >= n8) return;
  f32x8 a = ((const f32x8*)in)[i];
  bf16x8 o;
#pragma unroll
  for (int j = 0; j < 8; ++j) o[j] = (__bf16)a[j];
  ((bf16x8*)out)[i] = o;
}

// ---------------- prep: transpose [768][N] f32 -> [N][768] bf16 ----------------
__global__ __launch_bounds__(256) void transpose_cvt(const float* __restrict__ in,
                                                     __bf16* __restrict__ out, int N) {
  __shared__ __bf16 t[64][72];  // padded
  int kb = blockIdx.x * 64, nb = blockIdx.y * 64;
  int c = threadIdx.x & 63, r0 = threadIdx.x >> 6;
#pragma unroll
  for (int i = 0; i < 16; ++i) {
    int r = r0 * 16 + i;
    t[c][r] = (__bf16)in[(size_t)(kb + r) * N + nb + c];
  }
  __syncthreads();
#pragma unroll
  for (int i = 0; i < 16; ++i) {
    int r = r0 * 16 + i;
    out[(size_t)(nb + r) * DMODEL + kb + c] = t[r][c];
  }
}

// ---------------- shared GEMM core: C[128x128] += A[128xK] * Bt[128xK]^T ----------------
__device__ __forceinline__ void gemm128_bt(const __bf16* __restrict__ A,
                                           const __bf16* __restrict__ Bt,
                                           int m0, int n0, int K,
                                           __bf16* Alds, __bf16* Blds,
                                           f32x4 acc[4][4]) {
  const int tid = threadIdx.x;
  const int l = tid & 63, w = tid >> 6;
  const int wr = w >> 1, wc = w & 1;
  const int g = l >> 4, ln = l & 15;

  const int rr = tid >> 3;
  const int sx = (tid & 7) ^ (rr & 7);
  const __bf16* As = A + (size_t)(m0 + rr) * K + sx * 8;
  const __bf16* Bs = Bt + (size_t)(n0 + rr) * K + sx * 8;
  char* Ad = (char*)Alds + (w << 10);
  char* Bd = (char*)Blds + (w << 10);

  for (int k0 = 0; k0 < K; k0 += 64) {
#pragma unroll
    for (int i = 0; i < 4; ++i) {
      async16(As + (size_t)(i * 32) * K + k0, Ad + i * 4096);
      async16(Bs + (size_t)(i * 32) * K + k0, Bd + i * 4096);
    }
    __syncthreads();
#pragma unroll
    for (int kk = 0; kk < 2; ++kk) {
      bf16x8 af[4], bfr[4];
#pragma unroll
      for (int mi = 0; mi < 4; ++mi) {
        int row = wr * 64 + mi * 16 + ln;
        af[mi] = *(const bf16x8*)(Alds + row * 64 + ((((kk << 2) + g) ^ (row & 7)) << 3));
      }
#pragma unroll
      for (int ni = 0; ni < 4; ++ni) {
        int row = wc * 64 + ni * 16 + ln;
        bfr[ni] = *(const bf16x8*)(Blds + row * 64 + ((((kk << 2) + g) ^ (row & 7)) << 3));
      }
#pragma unroll
      for (int mi = 0; mi < 4; ++mi)
#pragma unroll
        for (int ni = 0; ni < 4; ++ni)
          acc[mi][ni] =
              __builtin_amdgcn_mfma_f32_16x16x32_bf16(af[mi], bfr[ni], acc[mi][ni], 0, 0, 0);
    }
    __syncthreads();
  }
}

// ---------------- GEMM1: qkv = xb @ Wqkv + bqkv; Q pre-scaled by 0.125*log2e;
// scatter Q,K [B,H,S,Hd]; V transposed [B,H,Hd,S] ----------------
__global__ __launch_bounds__(256) void gemm_qkv(const __bf16* __restrict__ xb,
                                                const __bf16* __restrict__ Wt,
                                                const float* __restrict__ bqkv,
                                                __bf16* __restrict__ Qo,
                                                __bf16* __restrict__ Ko,
                                                __bf16* __restrict__ Vto) {
  __shared__ __bf16 Alds[128 * 64];
  __shared__ __bf16 Blds[128 * 64];
  int bm = blockIdx.x & 63, bn = blockIdx.x >> 6;
  int m0 = bm * 128, n0 = bn * 128;
  f32x4 acc[4][4];
#pragma unroll
  for (int i = 0; i < 4; ++i)
#pragma unroll
    for (int j = 0; j < 4; ++j) acc[i][j] = f32x4_zero();
  gemm128_bt(xb, Wt, m0, n0, DMODEL, Alds, Blds, acc);

  const int l = threadIdx.x & 63, w = threadIdx.x >> 6;
  const int wr = w >> 1, wc = w & 1, g = l >> 4, ln = l & 15;
#pragma unroll
  for (int ni = 0; ni < 4; ++ni) {
    int ncol = n0 + wc * 64 + ni * 16 + ln;
    int which = ncol / DMODEL;  // 0=q 1=k 2=v (uniform per 16-col fragment)
    int dd = ncol - which * DMODEL;
    int h = dd >> 6, hd = dd & 63;
    float bias = bqkv[ncol];
    if (which == 2) {
#pragma unroll
      for (int mi = 0; mi < 4; ++mi)
#pragma unroll
        for (int r = 0; r < 4; ++r) {
          int mrow = m0 + wr * 64 + mi * 16 + 4 * g + r;
          int b = mrow >> 12, s = mrow & (S_LEN - 1);
          float v = acc[mi][ni][r] + bias;
          Vto[(((size_t)(b * NH + h) * HD) + hd) * S_LEN + s] = (__bf16)v;
        }
    } else {
      __bf16* op = (which == 0) ? Qo : Ko;
      const float scl = (which == 0) ? SM_SCALE_LOG2E : 1.0f;
#pragma unroll
      for (int mi = 0; mi < 4; ++mi)
#pragma unroll
        for (int r = 0; r < 4; ++r) {
          int mrow = m0 + wr * 64 + mi * 16 + 4 * g + r;
          int b = mrow >> 12, s = mrow & (S_LEN - 1);
          float v = (acc[mi][ni][r] + bias) * scl;
          op[((((size_t)b * NH + h) * S_LEN) + s) * HD + hd] = (__bf16)v;
        }
    }
  }
}

// ---------------- GEMM2: out = Yb @ Wout + bout (fp32 out) ----------------
__global__ __launch_bounds__(256) void gemm_out(const __bf16* __restrict__ yb,
                                                const __bf16* __restrict__ Wt,
                                                const float* __restrict__ bout,
                                                float* __restrict__ out) {
  __shared__ __bf16 Alds[128 * 64];
  __shared__ __bf16 Blds[128 * 64];
  int bm = blockIdx.x & 63, bn = blockIdx.x >> 6;
  int m0 = bm * 128, n0 = bn * 128;
  f32x4 acc[4][4];
#pragma unroll
  for (int i = 0; i < 4; ++i)
#pragma unroll
    for (int j = 0; j < 4; ++j) acc[i][j] = f32x4_zero();
  gemm128_bt(yb, Wt, m0, n0, DMODEL, Alds, Blds, acc);

  const int l = threadIdx.x & 63, w = threadIdx.x >> 6;
  const int wr = w >> 1, wc = w & 1, g = l >> 4, ln = l & 15;
#pragma unroll
  for (int ni = 0; ni < 4; ++ni) {
    int ncol = n0 + wc * 64 + ni * 16 + ln;
    float bias = bout[ncol];
#pragma unroll
    for (int mi = 0; mi < 4; ++mi)
#pragma unroll
      for (int r = 0; r < 4; ++r) {
        int mrow = m0 + wr * 64 + mi * 16 + 4 * g + r;
        out[(size_t)mrow * DMODEL + ncol] = acc[mi][ni][r] + bias;
      }
  }
}

// ---------------- causal flash attention v16: v14 body, 2 q-subtiles/wave ----------------
// v14's verified LDS layouts/staging (K [64kv][64d], V [64d][64kv], XOR-swizzled,
// double-buffered, one barrier/iter, global_load_lds DMA) with each wave now
// processing TWO 16-row q-subtiles (A: chunk rows 0-63 by wave, B: rows 64-127)
// against the same staged tile, sequentially reusing the same 2KB P-bounce.
// Halves block-iterations and barrier/staging cost per unit of compute; adds
// a second independent QK->softmax->PV chain (ILP). LDS stays 40KB -> 4/CU.
// Decomposition: 128-row chunks; c>=16 kv-split (exact partial slabs); c<16
// direct. 1152 units, all <=32 iters, heavy-first. A's diag tile = 2c (A skips
// tile 2c+1); B's diag = 2c+1. Split part0 never touches a mask.
__global__ __launch_bounds__(256) void attn_fwd16(const __bf16* __restrict__ Q,
                                                  const __bf16* __restrict__ K,
                                                  const __bf16* __restrict__ Vt,
                                                  __bf16* __restrict__ Y,
                                                  char* __restrict__ Po) {
  __shared__ __bf16 KVl[2][2][4096];  // [buf][K/V][8KB]: K [64kv][64d], V [64d][64kv]
  __shared__ char Plb[4][2048];       // per-wave P bounce [16 q][64 kv] pitch 128 + XOR

  const int tid = threadIdx.x;
  const int wv = tid >> 6, l = tid & 63;
  const int g = l >> 4, ln = l & 15;
  const int bi = blockIdx.x;
  const int xcd = bi & 7, j = bi >> 3;  // j in 0..143
  const int head = xcd * 3 + (j % 3);   // 3 heads per XCD
  const int r_ = j / 3;                 // rank 0..47, heavy-first

  int c, t0, t1, part;
  bool split;
  if (r_ < 32) {  // split chunks c=31..16, two kv halves each
    c = 31 - (r_ >> 1);
    part = r_ & 1;
    int h = c + 1;  // half of T = 2c+2 tiles
    t0 = part ? h : 0;
    t1 = part ? 2 * c + 2 : h;
    split = true;
  } else {  // direct chunks c=15..0
    c = 47 - r_;
    part = 0;
    t0 = 0;
    t1 = 2 * c + 2;
    split = false;
  }
  const int q0A = 128 * c + 16 * wv;
  const int q0B = q0A + 64;
  const int thr = 16 * wv + ln;         // chunk-local mask threshold (same for A,B)
  const int iA = 2 * c, iB = 2 * c + 1; // diag tile indices

  const size_t hb = (size_t)head * (S_LEN * HD);
  const __bf16* Qh = Q + hb;
  const __bf16* Kh = K + hb;
  const __bf16* Vh = Vt + hb;  // [HD][S]

  const int sw = (ln & 7) << 4;
  char* Pw = Plb[wv] + ln * 128;

  // staging lane geometry (identical to v14)
  const int r0 = tid >> 3;
  const int s0 = (tid & 7) ^ (r0 & 7);
  const size_t kL0 = (size_t)r0 * HD + s0 * 8;
  const size_t kL1 = kL0 + (size_t)32 * HD;
  const size_t vL0 = (size_t)r0 * S_LEN + s0 * 8;
  const size_t vL1 = vL0 + (size_t)32 * S_LEN;
  const int ldsoff = wv << 10;

  bf16x8 qfA[2], qfB[2];
#pragma unroll
  for (int t = 0; t < 2; ++t) {
    qfA[t] = *(const bf16x8*)(Qh + (size_t)(q0A + ln) * HD + 32 * t + 8 * g);
    qfB[t] = *(const bf16x8*)(Qh + (size_t)(q0B + ln) * HD + 32 * t + 8 * g);
  }

  bf16x8 ones;
#pragma unroll
  for (int t = 0; t < 8; ++t) ones[t] = (__bf16)1.0f;

  f32x4 oA[4], oB[4], o5A, o5B;
#pragma unroll
  for (int nt = 0; nt < 4; ++nt) {
    oA[nt] = f32x4_zero();
    oB[nt] = f32x4_zero();
  }
  o5A = f32x4_zero();
  o5B = f32x4_zero();

  // prologue: stage tile t0 into buf 0
  const __bf16* kq = Kh + (size_t)t0 * 64 * HD;
  const __bf16* vq = Vh + t0 * 64;
  {
    char* Kd = (char*)&KVl[0][0][0] + ldsoff;
    char* Vd = (char*)&KVl[0][1][0] + ldsoff;
    async16(kq + kL0, Kd);
    async16(kq + kL1, Kd + 4096);
    async16(vq + vL0, Vd);
    async16(vq + vL1, Vd + 4096);
    __syncthreads();
  }
  kq += (size_t)64 * HD;
  vq += 64;

  int cur = 0;
  for (int i = t0; i < t1; ++i) {
    const bool more = (i + 1) < t1;
    if (more) {  // DMA next tile into buf^1 (drained by end-of-iter barrier)
      char* Kd = (char*)&KVl[cur ^ 1][0][0] + ldsoff;
      char* Vd = (char*)&KVl[cur ^ 1][1][0] + ldsoff;
      async16(kq + kL0, Kd);
      async16(kq + kL1, Kd + 4096);
      async16(vq + vL0, Vd);
      async16(vq + vL1, Vd + 4096);
      kq += (size_t)64 * HD;
      vq += 64;
    }

    const __bf16* Kl = &KVl[cur][0][0];
    const __bf16* Vl = &KVl[cur][1][0];

    // ================= subtile A (skips tile 2c+1) =================
    if (i <= iA) {
      const bool diag = (i == iA);
      if (!diag) {
#pragma unroll
        for (int jt = 0; jt < 4; ++jt) {
          int row = 16 * jt + ln;
          bf16x8 kf0 = *(const bf16x8*)(Kl + row * 64 + ((g ^ (row & 7)) << 3));
          bf16x8 kf1 = *(const bf16x8*)(Kl + row * 64 + (((4 + g) ^ (row & 7)) << 3));
          f32x4 z = f32x4_zero();
          z = __builtin_amdgcn_mfma_f32_16x16x32_bf16(kf0, qfA[0], z, 0, 0, 0);
          z = __builtin_amdgcn_mfma_f32_16x16x32_bf16(kf1, qfA[1], z, 0, 0, 0);
          bf16x4 qd;
#pragma unroll
          for (int r = 0; r < 4; ++r) qd[r] = (__bf16)__builtin_exp2f(z[r]);
          *(bf16x4*)(Pw + ((32 * jt + 8 * g) ^ sw)) = qd;
        }
      } else {
#pragma unroll
        for (int jt = 0; jt < 4; ++jt) {
          int row = 16 * jt + ln;
          bf16x8 kf0 = *(const bf16x8*)(Kl + row * 64 + ((g ^ (row & 7)) << 3));
          bf16x8 kf1 = *(const bf16x8*)(Kl + row * 64 + (((4 + g) ^ (row & 7)) << 3));
          f32x4 z = f32x4_zero();
          z = __builtin_amdgcn_mfma_f32_16x16x32_bf16(kf0, qfA[0], z, 0, 0, 0);
          z = __builtin_amdgcn_mfma_f32_16x16x32_bf16(kf1, qfA[1], z, 0, 0, 0);
          bf16x4 qd;
#pragma unroll
          for (int r = 0; r < 4; ++r) {
            float pv = __builtin_exp2f(z[r]);
            if (16 * jt + 4 * g + r > thr) pv = 0.f;
            qd[r] = (__bf16)pv;
          }
          *(bf16x4*)(Pw + ((32 * jt + 8 * g) ^ sw)) = qd;
        }
      }
      bf16x8 pa0 = *(const bf16x8*)(Pw + ((16 * g) ^ sw));
      bf16x8 pa1 = *(const bf16x8*)(Pw + ((64 + 16 * g) ^ sw));
      __builtin_amdgcn_s_setprio(1);
      o5A = __builtin_amdgcn_mfma_f32_16x16x32_bf16(pa0, ones, o5A, 0, 0, 0);
      o5A = __builtin_amdgcn_mfma_f32_16x16x32_bf16(pa1, ones, o5A, 0, 0, 0);
#pragma unroll
      for (int nt = 0; nt < 4; ++nt) {
        int row = 16 * nt + ln;
        bf16x8 vf0 = *(const bf16x8*)(Vl + row * 64 + ((g ^ (row & 7)) << 3));
        bf16x8 vf1 = *(const bf16x8*)(Vl + row * 64 + (((4 + g) ^ (row & 7)) << 3));
        oA[nt] = __builtin_amdgcn_mfma_f32_16x16x32_bf16(pa0, vf0, oA[nt], 0, 0, 0);
        oA[nt] = __builtin_amdgcn_mfma_f32_16x16x32_bf16(pa1, vf1, oA[nt], 0, 0, 0);
      }
      __builtin_amdgcn_s_setprio(0);
    }

    // ================= subtile B (always active) =================
    {
      const bool diag = (i == iB);
      if (!diag) {
#pragma unroll
        for (int jt = 0; jt < 4; ++jt) {
          int row = 16 * jt + ln;
          bf16x8 kf0 = *(const bf16x8*)(Kl + row * 64 + ((g ^ (row & 7)) << 3));
          bf16x8 kf1 = *(const bf16x8*)(Kl + row * 64 + (((4 + g) ^ (row & 7)) << 3));
          f32x4 z = f32x4_zero();
          z = __builtin_amdgcn_mfma_f32_16x16x32_bf16(kf0, qfB[0], z, 0, 0, 0);
          z = __builtin_amdgcn_mfma_f32_16x16x32_bf16(kf1, qfB[1], z, 0, 0, 0);
          bf16x4 qd;
#pragma unroll
          for (int r = 0; r < 4; ++r) qd[r] = (__bf16)__builtin_exp2f(z[r]);
          *(bf16x4*)(Pw + ((32 * jt + 8 * g) ^ sw)) = qd;
        }
      } else {
#pragma unroll
        for (int jt = 0; jt < 4; ++jt) {
          int row = 16 * jt + ln;
          bf16x8 kf0 = *(const bf16x8*)(Kl + row * 64 + ((g ^ (row & 7)) << 3));
          bf16x8 kf1 = *(const bf16x8*)(Kl + row * 64 + (((4 + g) ^ (row & 7)) << 3));
          f32x4 z = f32x4_zero();
          z = __builtin_amdgcn_mfma_f32_16x16x32_bf16(kf0, qfB[0], z, 0, 0, 0);
          z = __builtin_amdgcn_mfma_f32_16x16x32_bf16(kf1, qfB[1], z, 0, 0, 0);
          bf16x4 qd;
#pragma unroll
          for (int r = 0; r < 4; ++r) {
            float pv = __builtin_exp2f(z[r]);
            if (16 * jt + 4 * g + r > thr) pv = 0.f;
            qd[r] = (__bf16)pv;
          }
          *(bf16x4*)(Pw + ((32 * jt + 8 * g) ^ sw)) = qd;
        }
      }
      bf16x8 pa0 = *(const bf16x8*)(Pw + ((16 * g) ^ sw));
      bf16x8 pa1 = *(const bf16x8*)(Pw + ((64 + 16 * g) ^ sw));
      __builtin_amdgcn_s_setprio(1);
      o5B = __builtin_amdgcn_mfma_f32_16x16x32_bf16(pa0, ones, o5B, 0, 0, 0);
      o5B = __builtin_amdgcn_mfma_f32_16x16x32_bf16(pa1, ones, o5B, 0, 0, 0);
#pragma unroll
      for (int nt = 0; nt < 4; ++nt) {
        int row = 16 * nt + ln;
        bf16x8 vf0 = *(const bf16x8*)(Vl + row * 64 + ((g ^ (row & 7)) << 3));
        bf16x8 vf1 = *(const bf16x8*)(Vl + row * 64 + (((4 + g) ^ (row & 7)) << 3));
        oB[nt] = __builtin_amdgcn_mfma_f32_16x16x32_bf16(pa0, vf0, oB[nt], 0, 0, 0);
        oB[nt] = __builtin_amdgcn_mfma_f32_16x16x32_bf16(pa1, vf1, oB[nt], 0, 0, 0);
      }
      __builtin_amdgcn_s_setprio(0);
    }

    if (more) __syncthreads();  // drains DMA (vmcnt0) + publishes buf^1
    cur ^= 1;
  }

  if (!split) {
    // direct write Y: lane holds O[q=4g+r][d=16nt+ln]
    const int bb = head / NH, hh = head - bb * NH;
    __bf16* Yp = Y + ((size_t)bb * S_LEN) * DMODEL + hh * HD;
#pragma unroll
    for (int r = 0; r < 4; ++r) {
      float invA = 1.0f / o5A[r];
      float invB = 1.0f / o5B[r];
      int qrA = q0A + 4 * g + r, qrB = q0B + 4 * g + r;
#pragma unroll
      for (int nt = 0; nt < 4; ++nt) {
        Yp[(size_t)qrA * DMODEL + 16 * nt + ln] = (__bf16)(oA[nt][r] * invA);
        Yp[(size_t)qrB * DMODEL + 16 * nt + ln] = (__bf16)(oB[nt][r] * invB);
      }
    }
  } else {
    // partial slab: O bf16 [128 rows][64 d] + rowsum f32 [128]
    char* slab = Po + (size_t)(((head << 4) + (c - 16)) * 2 + part) * SLAB_STRIDE;
#pragma unroll
    for (int r = 0; r < 4; ++r) {
      int rowA = 16 * wv + 4 * g + r, rowB = 64 + rowA;
#pragma unroll
      for (int nt = 0; nt < 4; ++nt) {
        *(__bf16*)(slab + (rowA * 64 + 16 * nt + ln) * 2) = (__bf16)oA[nt][r];
        *(__bf16*)(slab + (rowB * 64 + 16 * nt + ln) * 2) = (__bf16)oB[nt][r];
      }
      if (ln == 0) {
        *(float*)(slab + 16384 + rowA * 4) = o5A[r];
        *(float*)(slab + 16384 + rowB * 4) = o5B[r];
      }
    }
  }
}

// ---------------- combine split-chunk partials (128-row chunks, 32 rows/block) ----------------
__global__ __launch_bounds__(256) void attn_combine(const char* __restrict__ Po,
                                                    __bf16* __restrict__ Y) {
  const int blk = blockIdx.x;  // 0..1535 = (head, chunk-16, quarter)
  const int head = blk >> 6, rem = blk & 63;
  const int cc = rem >> 2, quarter = rem & 3;
  const int c = cc + 16;
  const char* s0 = Po + (size_t)(((head << 4) + cc) * 2) * SLAB_STRIDE;
  const char* s1 = s0 + SLAB_STRIDE;
  const int tid = threadIdx.x;
  const int row = quarter * 32 + (tid >> 3), d0 = (tid & 7) * 8;

  bf16x8 a = *(const bf16x8*)(s0 + (row * 64 + d0) * 2);
  bf16x8 b = *(const bf16x8*)(s1 + (row * 64 + d0) * 2);
  float rs = *(const float*)(s0 + 16384 + row * 4) + *(const float*)(s1 + 16384 + row * 4);
  float inv = 1.0f / rs;

  const int bb = head / NH, hh = head - bb * NH;
  __bf16* yp = Y + ((size_t)bb * S_LEN + 128 * c + row) * DMODEL + hh * HD + d0;
  bf16x8 o;
#pragma unroll
  for (int j = 0; j < 8; ++j) o[j] = (__bf16)(((float)a[j] + (float)b[j]) * inv);
  *(bf16x8*)yp = o;
}

extern "C" void kernel_launch(void* const* d_in, const int* in_sizes, int n_in,
                              void* d_out, int out_size, void* d_ws, size_t ws_size,
                              hipStream_t stream) {
  const float* x = (const float*)d_in[0];
  const float* Wqkv = (const float*)d_in[1];
  const float* bqkv = (const float*)d_in[2];
  const float* Wout = (const float*)d_in[3];
  const float* bout = (const float*)d_in[4];
  float* out = (float*)d_out;

  char* ws = (char*)d_ws;
  size_t off = 0;
  auto take = [&](size_t bytes) {
    char* p = ws + off;
    off += bytes;
    return p;
  };
  const size_t MD2 = (size_t)MTOT * DMODEL * 2;
  __bf16* xb = (__bf16*)take(MD2);
  __bf16* Wqkv_t = (__bf16*)take((size_t)3 * DMODEL * DMODEL * 2);
  __bf16* Wout_t = (__bf16*)take((size_t)DMODEL * DMODEL * 2);
  __bf16* Qb = (__bf16*)take(MD2);
  __bf16* Kb = (__bf16*)take(MD2);
  __bf16* Vtb = (__bf16*)take(MD2);
  __bf16* Yb = (__bf16*)take(MD2);
  char* Po = take((size_t)768 * SLAB_STRIDE);  // 24 heads x 16 split chunks x 2 parts

  int n8 = MTOT * DMODEL / 8;
  cvt_f32_bf16<<<(n8 + 255) / 256, 256, 0, stream>>>(x, xb, n8);
  transpose_cvt<<<dim3(DMODEL / 64, 3 * DMODEL / 64), 256, 0, stream>>>(Wqkv, Wqkv_t, 3 * DMODEL);
  transpose_cvt<<<dim3(DMODEL / 64, DMODEL / 64), 256, 0, stream>>>(Wout, Wout_t, DMODEL);
  gemm_qkv<<<64 * (3 * DMODEL / 128), 256, 0, stream>>>(xb, Wqkv_t, bqkv, Qb, Kb, Vtb);
  attn_fwd16<<<1152, 256, 0, stream>>>(Qb, Kb, Vtb, Yb, Po);
  attn_combine<<<1536, 256, 0, stream>>>(Po, Yb);
  gemm_out<<<64 * (DMODEL / 128), 256, 0, stream>>>(Yb, Wout_t, bout, out);
}

// Round 17
// 179.071 us; speedup vs baseline: 1.1890x; 1.1890x over previous
//
#include <hip/hip_runtime.h>

#define S_LEN 4096
#define NH 12
#define HD 64
#define DMODEL 768
#define BATCH 2
#define MTOT (BATCH * S_LEN) /* 8192 */

typedef __bf16 bf16x8 __attribute__((ext_vector_type(8)));
typedef __bf16 bf16x4 __attribute__((ext_vector_type(4)));
typedef float f32x4 __attribute__((ext_vector_type(4)));
typedef float f32x8 __attribute__((ext_vector_type(8)));

#define SM_SCALE_LOG2E 0.18033688f /* 0.125 * log2(e), folded into Q at GEMM1 */
#define SLAB_STRIDE 8448           /* 64x64 bf16 O (8192) + 64 f32 rowsum (256) */

__device__ __forceinline__ f32x4 f32x4_zero() {
  f32x4 z = {0.f, 0.f, 0.f, 0.f};
  return z;
}

// async global->LDS DMA, 16B per lane. LDS dest = wave-uniform base + lane*16
// (linear); swizzled layouts realized by pre-swizzling the per-lane GLOBAL
// source address (rule #21). Drained by the vmcnt(0) before s_barrier.
__device__ __forceinline__ void async16(const __bf16* g, void* l) {
  __builtin_amdgcn_global_load_lds(
      (const __attribute__((address_space(1))) void*)g,
      (__attribute__((address_space(3))) void*)l, 16, 0, 0);
}

// ---------------- prep: f32 -> bf16 (vectorized) ----------------
__global__ __launch_bounds__(256) void cvt_f32_bf16(const float* __restrict__ in,
                                                    __bf16* __restrict__ out, int n8) {
  int i = blockIdx.x * 256 + threadIdx.x;
  if (i >= n8) return;
  f32x8 a = ((const f32x8*)in)[i];
  bf16x8 o;
#pragma unroll
  for (int j = 0; j < 8; ++j) o[j] = (__bf16)a[j];
  ((bf16x8*)out)[i] = o;
}

// ---------------- prep: transpose [768][N] f32 -> [N][768] bf16 ----------------
__global__ __launch_bounds__(256) void transpose_cvt(const float* __restrict__ in,
                                                     __bf16* __restrict__ out, int N) {
  __shared__ __bf16 t[64][72];  // padded
  int kb = blockIdx.x * 64, nb = blockIdx.y * 64;
  int c = threadIdx.x & 63, r0 = threadIdx.x >> 6;
#pragma unroll
  for (int i = 0; i < 16; ++i) {
    int r = r0 * 16 + i;
    t[c][r] = (__bf16)in[(size_t)(kb + r) * N + nb + c];
  }
  __syncthreads();
#pragma unroll
  for (int i = 0; i < 16; ++i) {
    int r = r0 * 16 + i;
    out[(size_t)(nb + r) * DMODEL + kb + c] = t[r][c];
  }
}

// ---------------- shared GEMM core: C[128x128] += A[128xK] * Bt[128xK]^T ----------------
__device__ __forceinline__ void gemm128_bt(const __bf16* __restrict__ A,
                                           const __bf16* __restrict__ Bt,
                                           int m0, int n0, int K,
                                           __bf16* Alds, __bf16* Blds,
                                           f32x4 acc[4][4]) {
  const int tid = threadIdx.x;
  const int l = tid & 63, w = tid >> 6;
  const int wr = w >> 1, wc = w & 1;
  const int g = l >> 4, ln = l & 15;

  const int rr = tid >> 3;
  const int sx = (tid & 7) ^ (rr & 7);
  const __bf16* As = A + (size_t)(m0 + rr) * K + sx * 8;
  const __bf16* Bs = Bt + (size_t)(n0 + rr) * K + sx * 8;
  char* Ad = (char*)Alds + (w << 10);
  char* Bd = (char*)Blds + (w << 10);

  for (int k0 = 0; k0 < K; k0 += 64) {
#pragma unroll
    for (int i = 0; i < 4; ++i) {
      async16(As + (size_t)(i * 32) * K + k0, Ad + i * 4096);
      async16(Bs + (size_t)(i * 32) * K + k0, Bd + i * 4096);
    }
    __syncthreads();
#pragma unroll
    for (int kk = 0; kk < 2; ++kk) {
      bf16x8 af[4], bfr[4];
#pragma unroll
      for (int mi = 0; mi < 4; ++mi) {
        int row = wr * 64 + mi * 16 + ln;
        af[mi] = *(const bf16x8*)(Alds + row * 64 + ((((kk << 2) + g) ^ (row & 7)) << 3));
      }
#pragma unroll
      for (int ni = 0; ni < 4; ++ni) {
        int row = wc * 64 + ni * 16 + ln;
        bfr[ni] = *(const bf16x8*)(Blds + row * 64 + ((((kk << 2) + g) ^ (row & 7)) << 3));
      }
#pragma unroll
      for (int mi = 0; mi < 4; ++mi)
#pragma unroll
        for (int ni = 0; ni < 4; ++ni)
          acc[mi][ni] =
              __builtin_amdgcn_mfma_f32_16x16x32_bf16(af[mi], bfr[ni], acc[mi][ni], 0, 0, 0);
    }
    __syncthreads();
  }
}

// ---------------- GEMM1: qkv = xb @ Wqkv + bqkv; Q pre-scaled by 0.125*log2e;
// scatter Q,K [B,H,S,Hd]; V transposed [B,H,Hd,S] ----------------
__global__ __launch_bounds__(256) void gemm_qkv(const __bf16* __restrict__ xb,
                                                const __bf16* __restrict__ Wt,
                                                const float* __restrict__ bqkv,
                                                __bf16* __restrict__ Qo,
                                                __bf16* __restrict__ Ko,
                                                __bf16* __restrict__ Vto) {
  __shared__ __bf16 Alds[128 * 64];
  __shared__ __bf16 Blds[128 * 64];
  int bm = blockIdx.x & 63, bn = blockIdx.x >> 6;
  int m0 = bm * 128, n0 = bn * 128;
  f32x4 acc[4][4];
#pragma unroll
  for (int i = 0; i < 4; ++i)
#pragma unroll
    for (int j = 0; j < 4; ++j) acc[i][j] = f32x4_zero();
  gemm128_bt(xb, Wt, m0, n0, DMODEL, Alds, Blds, acc);

  const int l = threadIdx.x & 63, w = threadIdx.x >> 6;
  const int wr = w >> 1, wc = w & 1, g = l >> 4, ln = l & 15;
#pragma unroll
  for (int ni = 0; ni < 4; ++ni) {
    int ncol = n0 + wc * 64 + ni * 16 + ln;
    int which = ncol / DMODEL;  // 0=q 1=k 2=v (uniform per 16-col fragment)
    int dd = ncol - which * DMODEL;
    int h = dd >> 6, hd = dd & 63;
    float bias = bqkv[ncol];
    if (which == 2) {
#pragma unroll
      for (int mi = 0; mi < 4; ++mi)
#pragma unroll
        for (int r = 0; r < 4; ++r) {
          int mrow = m0 + wr * 64 + mi * 16 + 4 * g + r;
          int b = mrow >> 12, s = mrow & (S_LEN - 1);
          float v = acc[mi][ni][r] + bias;
          Vto[(((size_t)(b * NH + h) * HD) + hd) * S_LEN + s] = (__bf16)v;
        }
    } else {
      __bf16* op = (which == 0) ? Qo : Ko;
      const float scl = (which == 0) ? SM_SCALE_LOG2E : 1.0f;
#pragma unroll
      for (int mi = 0; mi < 4; ++mi)
#pragma unroll
        for (int r = 0; r < 4; ++r) {
          int mrow = m0 + wr * 64 + mi * 16 + 4 * g + r;
          int b = mrow >> 12, s = mrow & (S_LEN - 1);
          float v = (acc[mi][ni][r] + bias) * scl;
          op[((((size_t)b * NH + h) * S_LEN) + s) * HD + hd] = (__bf16)v;
        }
    }
  }
}

// ---------------- GEMM2: out = Yb @ Wout + bout (fp32 out) ----------------
__global__ __launch_bounds__(256) void gemm_out(const __bf16* __restrict__ yb,
                                                const __bf16* __restrict__ Wt,
                                                const float* __restrict__ bout,
                                                float* __restrict__ out) {
  __shared__ __bf16 Alds[128 * 64];
  __shared__ __bf16 Blds[128 * 64];
  int bm = blockIdx.x & 63, bn = blockIdx.x >> 6;
  int m0 = bm * 128, n0 = bn * 128;
  f32x4 acc[4][4];
#pragma unroll
  for (int i = 0; i < 4; ++i)
#pragma unroll
    for (int j = 0; j < 4; ++j) acc[i][j] = f32x4_zero();
  gemm128_bt(yb, Wt, m0, n0, DMODEL, Alds, Blds, acc);

  const int l = threadIdx.x & 63, w = threadIdx.x >> 6;
  const int wr = w >> 1, wc = w & 1, g = l >> 4, ln = l & 15;
#pragma unroll
  for (int ni = 0; ni < 4; ++ni) {
    int ncol = n0 + wc * 64 + ni * 16 + ln;
    float bias = bout[ncol];
#pragma unroll
    for (int mi = 0; mi < 4; ++mi)
#pragma unroll
      for (int r = 0; r < 4; ++r) {
        int mrow = m0 + wr * 64 + mi * 16 + 4 * g + r;
        out[(size_t)mrow * DMODEL + ncol] = acc[mi][ni][r] + bias;
      }
  }
}

// ---------------- causal flash attention v17: v14 body, uniform <=16-iter units ----------------
// Iteration body is v14 VERBATIM (the session's best: 4 waves share swizzled
// K/V LDS tiles via global_load_lds DMA, double-buffered, one barrier/iter).
// Only the decomposition changes: chunk c (64 q-rows) with T=c+1 kv-tiles is
// split into np=ceil(T/16) parts (np=1 for c<16 -> direct write; else exact
// partial slabs). All 3840 units are <=16 iterations -> finer backfill and a
// shorter drain tail (v14 measured 37.4% occupancy vs its 50% ceiling; the
// gap is unit-size quantization).
__global__ __launch_bounds__(256) void attn_fwd17(const __bf16* __restrict__ Q,
                                                  const __bf16* __restrict__ K,
                                                  const __bf16* __restrict__ Vt,
                                                  __bf16* __restrict__ Y,
                                                  char* __restrict__ Po) {
  __shared__ __bf16 KVl[2][2][4096];  // [buf][K/V][8KB]: K [64kv][64d], V [64d][64kv]
  __shared__ char Plb[4][2048];       // per-wave P bounce [16 q][64 kv] pitch 128 + XOR

  const int tid = threadIdx.x;
  const int wv = tid >> 6, l = tid & 63;
  const int g = l >> 4, ln = l & 15;
  const int bi = blockIdx.x;
  const int xcd = bi & 7, j = bi >> 3;  // j in 0..479
  const int head = xcd * 3 + (j % 3);   // 3 heads per XCD
  const int r_ = j / 3;                 // rank 0..159, heavy-first

  // rank -> (chunk c, part, np): class A c=63..48 np=4; B c=47..32 np=3;
  // C c=31..16 np=2; D c=15..0 direct.
  int c, part, np;
  bool split;
  if (r_ < 64) {
    c = 63 - (r_ >> 2);
    part = r_ & 3;
    np = 4;
    split = true;
  } else if (r_ < 112) {
    int q = r_ - 64;
    c = 47 - q / 3;
    part = q % 3;
    np = 3;
    split = true;
  } else if (r_ < 144) {
    int q = r_ - 112;
    c = 31 - (q >> 1);
    part = q & 1;
    np = 2;
    split = true;
  } else {
    c = 159 - r_;
    part = 0;
    np = 1;
    split = false;
  }
  const int T = c + 1;
  const int base = T / np, rem = T % np;
  const int t0 = part * base + (part < rem ? part : rem);
  const int t1 = t0 + base + (part < rem ? 1 : 0);

  const int q0 = 64 * c + 16 * wv;
  const int thr = 16 * wv + ln;        // chunk-local mask threshold
  const bool hasDiag = (t1 == T);      // last part owns the diag tile

  const size_t hb = (size_t)head * (S_LEN * HD);
  const __bf16* Qh = Q + hb;
  const __bf16* Kh = K + hb;
  const __bf16* Vh = Vt + hb;  // [HD][S]

  const int sw = (ln & 7) << 4;
  char* Pw = Plb[wv] + ln * 128;

  // staging lane geometry (identical to v14)
  const int r0 = tid >> 3;
  const int s0 = (tid & 7) ^ (r0 & 7);
  const size_t kL0 = (size_t)r0 * HD + s0 * 8;
  const size_t kL1 = kL0 + (size_t)32 * HD;
  const size_t vL0 = (size_t)r0 * S_LEN + s0 * 8;
  const size_t vL1 = vL0 + (size_t)32 * S_LEN;
  const int ldsoff = wv << 10;

  bf16x8 qf[2];
#pragma unroll
  for (int t = 0; t < 2; ++t)
    qf[t] = *(const bf16x8*)(Qh + (size_t)(q0 + ln) * HD + 32 * t + 8 * g);

  bf16x8 ones;
#pragma unroll
  for (int t = 0; t < 8; ++t) ones[t] = (__bf16)1.0f;

  f32x4 o[4], o5;
#pragma unroll
  for (int nt = 0; nt < 4; ++nt) o[nt] = f32x4_zero();
  o5 = f32x4_zero();

  // prologue: stage tile t0 into buf 0
  const __bf16* kq = Kh + (size_t)t0 * 64 * HD;
  const __bf16* vq = Vh + t0 * 64;
  {
    char* Kd = (char*)&KVl[0][0][0] + ldsoff;
    char* Vd = (char*)&KVl[0][1][0] + ldsoff;
    async16(kq + kL0, Kd);
    async16(kq + kL1, Kd + 4096);
    async16(vq + vL0, Vd);
    async16(vq + vL1, Vd + 4096);
    __syncthreads();
  }
  kq += (size_t)64 * HD;
  vq += 64;

  int cur = 0;
  for (int i = t0; i < t1; ++i) {
    const bool more = (i + 1) < t1;
    if (more) {  // DMA next tile into buf^1 (drained by end-of-iter barrier)
      char* Kd = (char*)&KVl[cur ^ 1][0][0] + ldsoff;
      char* Vd = (char*)&KVl[cur ^ 1][1][0] + ldsoff;
      async16(kq + kL0, Kd);
      async16(kq + kL1, Kd + 4096);
      async16(vq + vL0, Vd);
      async16(vq + vL1, Vd + 4096);
      kq += (size_t)64 * HD;
      vq += 64;
    }

    const __bf16* Kl = &KVl[cur][0][0];
    const __bf16* Vl = &KVl[cur][1][0];
    const bool diag = hasDiag && (i == c);

    // ---- QK^T + fused softmax -> P bounce ----
    if (!diag) {
#pragma unroll
      for (int jt = 0; jt < 4; ++jt) {
        int row = 16 * jt + ln;
        bf16x8 kf0 = *(const bf16x8*)(Kl + row * 64 + ((g ^ (row & 7)) << 3));
        bf16x8 kf1 = *(const bf16x8*)(Kl + row * 64 + (((4 + g) ^ (row & 7)) << 3));
        f32x4 z = f32x4_zero();
        z = __builtin_amdgcn_mfma_f32_16x16x32_bf16(kf0, qf[0], z, 0, 0, 0);
        z = __builtin_amdgcn_mfma_f32_16x16x32_bf16(kf1, qf[1], z, 0, 0, 0);
        bf16x4 qd;
#pragma unroll
        for (int r = 0; r < 4; ++r) qd[r] = (__bf16)__builtin_exp2f(z[r]);
        *(bf16x4*)(Pw + ((32 * jt + 8 * g) ^ sw)) = qd;
      }
    } else {
#pragma unroll
      for (int jt = 0; jt < 4; ++jt) {
        int row = 16 * jt + ln;
        bf16x8 kf0 = *(const bf16x8*)(Kl + row * 64 + ((g ^ (row & 7)) << 3));
        bf16x8 kf1 = *(const bf16x8*)(Kl + row * 64 + (((4 + g) ^ (row & 7)) << 3));
        f32x4 z = f32x4_zero();
        z = __builtin_amdgcn_mfma_f32_16x16x32_bf16(kf0, qf[0], z, 0, 0, 0);
        z = __builtin_amdgcn_mfma_f32_16x16x32_bf16(kf1, qf[1], z, 0, 0, 0);
        bf16x4 qd;
#pragma unroll
        for (int r = 0; r < 4; ++r) {
          float pv = __builtin_exp2f(z[r]);
          if (16 * jt + 4 * g + r > thr) pv = 0.f;
          qd[r] = (__bf16)pv;
        }
        *(bf16x4*)(Pw + ((32 * jt + 8 * g) ^ sw)) = qd;
      }
    }

    // ---- PV + ones row-sum ----
    bf16x8 pa0 = *(const bf16x8*)(Pw + ((16 * g) ^ sw));
    bf16x8 pa1 = *(const bf16x8*)(Pw + ((64 + 16 * g) ^ sw));
    __builtin_amdgcn_s_setprio(1);
    o5 = __builtin_amdgcn_mfma_f32_16x16x32_bf16(pa0, ones, o5, 0, 0, 0);
    o5 = __builtin_amdgcn_mfma_f32_16x16x32_bf16(pa1, ones, o5, 0, 0, 0);
#pragma unroll
    for (int nt = 0; nt < 4; ++nt) {
      int row = 16 * nt + ln;
      bf16x8 vf0 = *(const bf16x8*)(Vl + row * 64 + ((g ^ (row & 7)) << 3));
      bf16x8 vf1 = *(const bf16x8*)(Vl + row * 64 + (((4 + g) ^ (row & 7)) << 3));
      o[nt] = __builtin_amdgcn_mfma_f32_16x16x32_bf16(pa0, vf0, o[nt], 0, 0, 0);
      o[nt] = __builtin_amdgcn_mfma_f32_16x16x32_bf16(pa1, vf1, o[nt], 0, 0, 0);
    }
    __builtin_amdgcn_s_setprio(0);

    if (more) __syncthreads();  // drains DMA (vmcnt0) + publishes buf^1
    cur ^= 1;
  }

  if (!split) {
    // direct write Y: lane holds O[q=4g+r][d=16nt+ln]
    const int bb = head / NH, hh = head - bb * NH;
    __bf16* Yp = Y + ((size_t)bb * S_LEN) * DMODEL + hh * HD;
#pragma unroll
    for (int r = 0; r < 4; ++r) {
      float inv = 1.0f / o5[r];
      int qr = q0 + 4 * g + r;
#pragma unroll
      for (int nt = 0; nt < 4; ++nt)
        Yp[(size_t)qr * DMODEL + 16 * nt + ln] = (__bf16)(o[nt][r] * inv);
    }
  } else {
    // partial slab: O bf16 [64 rows][64 d] + rowsum f32 [64]
    // per-head slab offsets: C(c16..31,np2)->0..31, B(c32..47,np3)->32..79,
    // A(c48..63,np4)->80..143
    int soff;
    if (c < 32) soff = (c - 16) * 2 + part;
    else if (c < 48) soff = 32 + (c - 32) * 3 + part;
    else soff = 80 + (c - 48) * 4 + part;
    char* slab = Po + ((size_t)head * 144 + soff) * SLAB_STRIDE;
#pragma unroll
    for (int r = 0; r < 4; ++r) {
      int rowL = 16 * wv + 4 * g + r;
#pragma unroll
      for (int nt = 0; nt < 4; ++nt)
        *(__bf16*)(slab + (rowL * 64 + 16 * nt + ln) * 2) = (__bf16)o[nt][r];
      if (ln == 0) *(float*)(slab + 8192 + rowL * 4) = o5[r];
    }
  }
}

// ---------------- combine split-chunk partials (sum np slabs; 32 rows/block) ----------------
__global__ __launch_bounds__(256) void attn_combine(const char* __restrict__ Po,
                                                    __bf16* __restrict__ Y) {
  const int blk = blockIdx.x;  // 0..2303 = head * 96 + (chunk-16)*2 + half
  const int head = blk / 96, rem = blk - head * 96;
  const int cc = rem >> 1, half = rem & 1;
  const int c = cc + 16;
  int np, boff;
  if (c < 32) {
    np = 2;
    boff = (c - 16) * 2;
  } else if (c < 48) {
    np = 3;
    boff = 32 + (c - 32) * 3;
  } else {
    np = 4;
    boff = 80 + (c - 48) * 4;
  }
  const char* s = Po + ((size_t)head * 144 + boff) * SLAB_STRIDE;
  const int tid = threadIdx.x;
  const int row = half * 32 + (tid >> 3), d0 = (tid & 7) * 8;

  float acc[8] = {0.f, 0.f, 0.f, 0.f, 0.f, 0.f, 0.f, 0.f};
  float rs = 0.f;
  for (int p = 0; p < np; ++p) {
    bf16x8 a = *(const bf16x8*)(s + (size_t)p * SLAB_STRIDE + (row * 64 + d0) * 2);
#pragma unroll
    for (int j = 0; j < 8; ++j) acc[j] += (float)a[j];
    rs += *(const float*)(s + (size_t)p * SLAB_STRIDE + 8192 + row * 4);
  }
  float inv = 1.0f / rs;

  const int bb = head / NH, hh = head - bb * NH;
  __bf16* yp = Y + ((size_t)bb * S_LEN + 64 * c + row) * DMODEL + hh * HD + d0;
  bf16x8 o;
#pragma unroll
  for (int j = 0; j < 8; ++j) o[j] = (__bf16)(acc[j] * inv);
  *(bf16x8*)yp = o;
}

extern "C" void kernel_launch(void* const* d_in, const int* in_sizes, int n_in,
                              void* d_out, int out_size, void* d_ws, size_t ws_size,
                              hipStream_t stream) {
  const float* x = (const float*)d_in[0];
  const float* Wqkv = (const float*)d_in[1];
  const float* bqkv = (const float*)d_in[2];
  const float* Wout = (const float*)d_in[3];
  const float* bout = (const float*)d_in[4];
  float* out = (float*)d_out;

  char* ws = (char*)d_ws;
  size_t off = 0;
  auto take = [&](size_t bytes) {
    char* p = ws + off;
    off += bytes;
    return p;
  };
  const size_t MD2 = (size_t)MTOT * DMODEL * 2;
  __bf16* xb = (__bf16*)take(MD2);
  __bf16* Wqkv_t = (__bf16*)take((size_t)3 * DMODEL * DMODEL * 2);
  __bf16* Wout_t = (__bf16*)take((size_t)DMODEL * DMODEL * 2);
  __bf16* Qb = (__bf16*)take(MD2);
  __bf16* Kb = (__bf16*)take(MD2);
  __bf16* Vtb = (__bf16*)take(MD2);
  __bf16* Yb = (__bf16*)take(MD2);
  char* Po = take((size_t)24 * 144 * SLAB_STRIDE);  // 24 heads x 144 slabs

  int n8 = MTOT * DMODEL / 8;
  cvt_f32_bf16<<<(n8 + 255) / 256, 256, 0, stream>>>(x, xb, n8);
  transpose_cvt<<<dim3(DMODEL / 64, 3 * DMODEL / 64), 256, 0, stream>>>(Wqkv, Wqkv_t, 3 * DMODEL);
  transpose_cvt<<<dim3(DMODEL / 64, DMODEL / 64), 256, 0, stream>>>(Wout, Wout_t, DMODEL);
  gemm_qkv<<<64 * (3 * DMODEL / 128), 256, 0, stream>>>(xb, Wqkv_t, bqkv, Qb, Kb, Vtb);
  attn_fwd17<<<3840, 256, 0, stream>>>(Qb, Kb, Vtb, Yb, Po);
  attn_combine<<<2304, 256, 0, stream>>>(Po, Yb);
  gemm_out<<<64 * (DMODEL / 128), 256, 0, stream>>>(Yb, Wout_t, bout, out);
}

// Round 18
// 172.412 us; speedup vs baseline: 1.2349x; 1.0386x over previous
//
#include <hip/hip_runtime.h>

#define S_LEN 4096
#define NH 12
#define HD 64
#define DMODEL 768
#define BATCH 2
#define MTOT (BATCH * S_LEN) /* 8192 */

typedef __bf16 bf16x8 __attribute__((ext_vector_type(8)));
typedef __bf16 bf16x4 __attribute__((ext_vector_type(4)));
typedef float f32x4 __attribute__((ext_vector_type(4)));
typedef float f32x8 __attribute__((ext_vector_type(8)));

#define SM_SCALE_LOG2E 0.18033688f /* 0.125 * log2(e), folded into Q at GEMM1 */
#define SLAB_STRIDE 16896          /* 128x64 bf16 O (16384) + 128 f32 rowsum (512) */

__device__ __forceinline__ f32x4 f32x4_zero() {
  f32x4 z = {0.f, 0.f, 0.f, 0.f};
  return z;
}

// async global->LDS DMA, 16B per lane. LDS dest = wave-uniform base + lane*16
// (linear); swizzled layouts realized by pre-swizzling the per-lane GLOBAL
// source address (rule #21). Drained by the vmcnt(0) before s_barrier.
__device__ __forceinline__ void async16(const __bf16* g, void* l) {
  __builtin_amdgcn_global_load_lds(
      (const __attribute__((address_space(1))) void*)g,
      (__attribute__((address_space(3))) void*)l, 16, 0, 0);
}

// ---------------- prep: f32 -> bf16 (vectorized) ----------------
__global__ __launch_bounds__(256) void cvt_f32_bf16(const float* __restrict__ in,
                                                    __bf16* __restrict__ out, int n8) {
  int i = blockIdx.x * 256 + threadIdx.x;
  if (i >= n8) return;
  f32x8 a = ((const f32x8*)in)[i];
  bf16x8 o;
#pragma unroll
  for (int j = 0; j < 8; ++j) o[j] = (__bf16)a[j];
  ((bf16x8*)out)[i] = o;
}

// ---------------- prep: transpose [768][N] f32 -> [N][768] bf16 ----------------
__global__ __launch_bounds__(256) void transpose_cvt(const float* __restrict__ in,
                                                     __bf16* __restrict__ out, int N) {
  __shared__ __bf16 t[64][72];  // padded
  int kb = blockIdx.x * 64, nb = blockIdx.y * 64;
  int c = threadIdx.x & 63, r0 = threadIdx.x >> 6;
#pragma unroll
  for (int i = 0; i < 16; ++i) {
    int r = r0 * 16 + i;
    t[c][r] = (__bf16)in[(size_t)(kb + r) * N + nb + c];
  }
  __syncthreads();
#pragma unroll
  for (int i = 0; i < 16; ++i) {
    int r = r0 * 16 + i;
    out[(size_t)(nb + r) * DMODEL + kb + c] = t[r][c];
  }
}

// ---------------- shared GEMM core: C[128x128] += A[128xK] * Bt[128xK]^T ----------------
__device__ __forceinline__ void gemm128_bt(const __bf16* __restrict__ A,
                                           const __bf16* __restrict__ Bt,
                                           int m0, int n0, int K,
                                           __bf16* Alds, __bf16* Blds,
                                           f32x4 acc[4][4]) {
  const int tid = threadIdx.x;
  const int l = tid & 63, w = tid >> 6;
  const int wr = w >> 1, wc = w & 1;
  const int g = l >> 4, ln = l & 15;

  const int rr = tid >> 3;
  const int sx = (tid & 7) ^ (rr & 7);
  const __bf16* As = A + (size_t)(m0 + rr) * K + sx * 8;
  const __bf16* Bs = Bt + (size_t)(n0 + rr) * K + sx * 8;
  char* Ad = (char*)Alds + (w << 10);
  char* Bd = (char*)Blds + (w << 10);

  for (int k0 = 0; k0 < K; k0 += 64) {
#pragma unroll
    for (int i = 0; i < 4; ++i) {
      async16(As + (size_t)(i * 32) * K + k0, Ad + i * 4096);
      async16(Bs + (size_t)(i * 32) * K + k0, Bd + i * 4096);
    }
    __syncthreads();
#pragma unroll
    for (int kk = 0; kk < 2; ++kk) {
      bf16x8 af[4], bfr[4];
#pragma unroll
      for (int mi = 0; mi < 4; ++mi) {
        int row = wr * 64 + mi * 16 + ln;
        af[mi] = *(const bf16x8*)(Alds + row * 64 + ((((kk << 2) + g) ^ (row & 7)) << 3));
      }
#pragma unroll
      for (int ni = 0; ni < 4; ++ni) {
        int row = wc * 64 + ni * 16 + ln;
        bfr[ni] = *(const bf16x8*)(Blds + row * 64 + ((((kk << 2) + g) ^ (row & 7)) << 3));
      }
#pragma unroll
      for (int mi = 0; mi < 4; ++mi)
#pragma unroll
        for (int ni = 0; ni < 4; ++ni)
          acc[mi][ni] =
              __builtin_amdgcn_mfma_f32_16x16x32_bf16(af[mi], bfr[ni], acc[mi][ni], 0, 0, 0);
    }
    __syncthreads();
  }
}

// ---------------- GEMM1: qkv = xb @ Wqkv + bqkv; Q pre-scaled by 0.125*log2e;
// scatter Q,K [B,H,S,Hd]; V transposed [B,H,Hd,S] ----------------
__global__ __launch_bounds__(256) void gemm_qkv(const __bf16* __restrict__ xb,
                                                const __bf16* __restrict__ Wt,
                                                const float* __restrict__ bqkv,
                                                __bf16* __restrict__ Qo,
                                                __bf16* __restrict__ Ko,
                                                __bf16* __restrict__ Vto) {
  __shared__ __bf16 Alds[128 * 64];
  __shared__ __bf16 Blds[128 * 64];
  int bm = blockIdx.x & 63, bn = blockIdx.x >> 6;
  int m0 = bm * 128, n0 = bn * 128;
  f32x4 acc[4][4];
#pragma unroll
  for (int i = 0; i < 4; ++i)
#pragma unroll
    for (int j = 0; j < 4; ++j) acc[i][j] = f32x4_zero();
  gemm128_bt(xb, Wt, m0, n0, DMODEL, Alds, Blds, acc);

  const int l = threadIdx.x & 63, w = threadIdx.x >> 6;
  const int wr = w >> 1, wc = w & 1, g = l >> 4, ln = l & 15;
#pragma unroll
  for (int ni = 0; ni < 4; ++ni) {
    int ncol = n0 + wc * 64 + ni * 16 + ln;
    int which = ncol / DMODEL;  // 0=q 1=k 2=v (uniform per 16-col fragment)
    int dd = ncol - which * DMODEL;
    int h = dd >> 6, hd = dd & 63;
    float bias = bqkv[ncol];
    if (which == 2) {
#pragma unroll
      for (int mi = 0; mi < 4; ++mi)
#pragma unroll
        for (int r = 0; r < 4; ++r) {
          int mrow = m0 + wr * 64 + mi * 16 + 4 * g + r;
          int b = mrow >> 12, s = mrow & (S_LEN - 1);
          float v = acc[mi][ni][r] + bias;
          Vto[(((size_t)(b * NH + h) * HD) + hd) * S_LEN + s] = (__bf16)v;
        }
    } else {
      __bf16* op = (which == 0) ? Qo : Ko;
      const float scl = (which == 0) ? SM_SCALE_LOG2E : 1.0f;
#pragma unroll
      for (int mi = 0; mi < 4; ++mi)
#pragma unroll
        for (int r = 0; r < 4; ++r) {
          int mrow = m0 + wr * 64 + mi * 16 + 4 * g + r;
          int b = mrow >> 12, s = mrow & (S_LEN - 1);
          float v = (acc[mi][ni][r] + bias) * scl;
          op[((((size_t)b * NH + h) * S_LEN) + s) * HD + hd] = (__bf16)v;
        }
    }
  }
}

// ---------------- GEMM2: out = Yb @ Wout + bout (fp32 out) ----------------
__global__ __launch_bounds__(256) void gemm_out(const __bf16* __restrict__ yb,
                                                const __bf16* __restrict__ Wt,
                                                const float* __restrict__ bout,
                                                float* __restrict__ out) {
  __shared__ __bf16 Alds[128 * 64];
  __shared__ __bf16 Blds[128 * 64];
  int bm = blockIdx.x & 63, bn = blockIdx.x >> 6;
  int m0 = bm * 128, n0 = bn * 128;
  f32x4 acc[4][4];
#pragma unroll
  for (int i = 0; i < 4; ++i)
#pragma unroll
    for (int j = 0; j < 4; ++j) acc[i][j] = f32x4_zero();
  gemm128_bt(yb, Wt, m0, n0, DMODEL, Alds, Blds, acc);

  const int l = threadIdx.x & 63, w = threadIdx.x >> 6;
  const int wr = w >> 1, wc = w & 1, g = l >> 4, ln = l & 15;
#pragma unroll
  for (int ni = 0; ni < 4; ++ni) {
    int ncol = n0 + wc * 64 + ni * 16 + ln;
    float bias = bout[ncol];
#pragma unroll
    for (int mi = 0; mi < 4; ++mi)
#pragma unroll
      for (int r = 0; r < 4; ++r) {
        int mrow = m0 + wr * 64 + mi * 16 + 4 * g + r;
        out[(size_t)mrow * DMODEL + ncol] = acc[mi][ni][r] + bias;
      }
  }
}

// ---------------- causal flash attention v18: 8-wave blocks, shared KV pipeline ----------------
// Per-wave body identical to v17 (QK swapped MFMA, fused exp2 softmax, P-bounce,
// PV + ones rowsum; same K/V LDS layouts and XOR swizzles). Packaging: 512-thread
// blocks = 8 waves share ONE K/V double-buffer -> LDS 48KB (32 KV + 16 P) ->
// 3 blocks/CU x 8 waves = 24 waves/CU (75% ceiling; v17: 16).
// Chunk = 128 q-rows (wave wv owns rows 128c+16wv..+15); generic per-tile mask
// via rel = q0-kv0 (full / partial / skip; barrier uniform). Decomposition:
// np = ceil(T/16) kv-parts (T = 2c+2 tiles), all 1920 units <=16 iters,
// heavy-first, XCD head affinity; exact partial slabs + combine.
__global__ __launch_bounds__(512) void attn_fwd18(const __bf16* __restrict__ Q,
                                                  const __bf16* __restrict__ K,
                                                  const __bf16* __restrict__ Vt,
                                                  __bf16* __restrict__ Y,
                                                  char* __restrict__ Po) {
  __shared__ __bf16 KVl[2][2][4096];  // [buf][K/V][8KB]: K [64kv][64d], V [64d][64kv]
  __shared__ char Plb[8][2048];       // per-wave P bounce [16 q][64 kv] pitch 128 + XOR

  const int tid = threadIdx.x;
  const int wv = tid >> 6, l = tid & 63;
  const int g = l >> 4, ln = l & 15;
  const int bi = blockIdx.x;
  const int xcd = bi & 7, j = bi >> 3;  // j in 0..239
  const int head = xcd * 3 + (j % 3);   // 3 heads per XCD
  const int r_ = j / 3;                 // rank 0..79, heavy-first

  // rank -> (chunk c of 128 rows, part, np); T = 2c+2 kv-tiles
  int c, part, np;
  bool split;
  if (r_ < 32) {  // c=31..24, np=4
    c = 31 - (r_ >> 2);
    part = r_ & 3;
    np = 4;
    split = true;
  } else if (r_ < 56) {  // c=23..16, np=3
    int q = r_ - 32;
    c = 23 - q / 3;
    part = q % 3;
    np = 3;
    split = true;
  } else if (r_ < 72) {  // c=15..8, np=2
    int q = r_ - 56;
    c = 15 - (q >> 1);
    part = q & 1;
    np = 2;
    split = true;
  } else {  // c=7..0, direct
    c = 79 - r_;
    part = 0;
    np = 1;
    split = false;
  }
  const int T = 2 * c + 2;
  const int base = T / np, rem = T % np;
  const int t0 = part * base + (part < rem ? part : rem);
  const int t1 = t0 + base + (part < rem ? 1 : 0);

  const int q0 = 128 * c + 16 * wv;  // wave's first q row (global)

  const size_t hb = (size_t)head * (S_LEN * HD);
  const __bf16* Qh = Q + hb;
  const __bf16* Kh = K + hb;
  const __bf16* Vh = Vt + hb;  // [HD][S]

  const int sw = (ln & 7) << 4;
  char* Pw = Plb[wv] + ln * 128;

  // staging: 512 threads cover the 8KB tile in one shot. granule tid ->
  // row tid>>3, linear slot tid&7 holds source slot (tid&7)^(row&7).
  const int r0 = tid >> 3;
  const int s0 = (tid & 7) ^ (r0 & 7);
  const size_t kL = (size_t)r0 * HD + s0 * 8;
  const size_t vL = (size_t)r0 * S_LEN + s0 * 8;
  const int ldsoff = wv << 10;  // wave-uniform dest base (lane*16 added by HW)

  bf16x8 qf[2];
#pragma unroll
  for (int t = 0; t < 2; ++t)
    qf[t] = *(const bf16x8*)(Qh + (size_t)(q0 + ln) * HD + 32 * t + 8 * g);

  bf16x8 ones;
#pragma unroll
  for (int t = 0; t < 8; ++t) ones[t] = (__bf16)1.0f;

  f32x4 o[4], o5;
#pragma unroll
  for (int nt = 0; nt < 4; ++nt) o[nt] = f32x4_zero();
  o5 = f32x4_zero();

  // prologue: stage tile t0 into buf 0
  const __bf16* kq = Kh + (size_t)t0 * 64 * HD;
  const __bf16* vq = Vh + t0 * 64;
  {
    async16(kq + kL, (char*)&KVl[0][0][0] + ldsoff);
    async16(vq + vL, (char*)&KVl[0][1][0] + ldsoff);
    __syncthreads();
  }
  kq += (size_t)64 * HD;
  vq += 64;

  int cur = 0;
  for (int i = t0; i < t1; ++i) {
    const bool more = (i + 1) < t1;
    if (more) {  // DMA next tile into buf^1 (drained by end-of-iter barrier)
      async16(kq + kL, (char*)&KVl[cur ^ 1][0][0] + ldsoff);
      async16(vq + vL, (char*)&KVl[cur ^ 1][1][0] + ldsoff);
      kq += (size_t)64 * HD;
      vq += 64;
    }

    const __bf16* Kl = &KVl[cur][0][0];
    const __bf16* Vl = &KVl[cur][1][0];
    const int rel = q0 - 64 * i;  // >=63 full; <=-16 fully masked; else partial

    if (rel > -16) {
      // ---- QK^T + fused softmax -> P bounce ----
      if (rel >= 63) {
#pragma unroll
        for (int jt = 0; jt < 4; ++jt) {
          int row = 16 * jt + ln;
          bf16x8 kf0 = *(const bf16x8*)(Kl + row * 64 + ((g ^ (row & 7)) << 3));
          bf16x8 kf1 = *(const bf16x8*)(Kl + row * 64 + (((4 + g) ^ (row & 7)) << 3));
          f32x4 z = f32x4_zero();
          z = __builtin_amdgcn_mfma_f32_16x16x32_bf16(kf0, qf[0], z, 0, 0, 0);
          z = __builtin_amdgcn_mfma_f32_16x16x32_bf16(kf1, qf[1], z, 0, 0, 0);
          bf16x4 qd;
#pragma unroll
          for (int r = 0; r < 4; ++r) qd[r] = (__bf16)__builtin_exp2f(z[r]);
          *(bf16x4*)(Pw + ((32 * jt + 8 * g) ^ sw)) = qd;
        }
      } else {
        const int thr = rel + ln;
#pragma unroll
        for (int jt = 0; jt < 4; ++jt) {
          int row = 16 * jt + ln;
          bf16x8 kf0 = *(const bf16x8*)(Kl + row * 64 + ((g ^ (row & 7)) << 3));
          bf16x8 kf1 = *(const bf16x8*)(Kl + row * 64 + (((4 + g) ^ (row & 7)) << 3));
          f32x4 z = f32x4_zero();
          z = __builtin_amdgcn_mfma_f32_16x16x32_bf16(kf0, qf[0], z, 0, 0, 0);
          z = __builtin_amdgcn_mfma_f32_16x16x32_bf16(kf1, qf[1], z, 0, 0, 0);
          bf16x4 qd;
#pragma unroll
          for (int r = 0; r < 4; ++r) {
            float pv = __builtin_exp2f(z[r]);
            if (16 * jt + 4 * g + r > thr) pv = 0.f;
            qd[r] = (__bf16)pv;
          }
          *(bf16x4*)(Pw + ((32 * jt + 8 * g) ^ sw)) = qd;
        }
      }

      // ---- PV + ones row-sum ----
      bf16x8 pa0 = *(const bf16x8*)(Pw + ((16 * g) ^ sw));
      bf16x8 pa1 = *(const bf16x8*)(Pw + ((64 + 16 * g) ^ sw));
      __builtin_amdgcn_s_setprio(1);
      o5 = __builtin_amdgcn_mfma_f32_16x16x32_bf16(pa0, ones, o5, 0, 0, 0);
      o5 = __builtin_amdgcn_mfma_f32_16x16x32_bf16(pa1, ones, o5, 0, 0, 0);
#pragma unroll
      for (int nt = 0; nt < 4; ++nt) {
        int row = 16 * nt + ln;
        bf16x8 vf0 = *(const bf16x8*)(Vl + row * 64 + ((g ^ (row & 7)) << 3));
        bf16x8 vf1 = *(const bf16x8*)(Vl + row * 64 + (((4 + g) ^ (row & 7)) << 3));
        o[nt] = __builtin_amdgcn_mfma_f32_16x16x32_bf16(pa0, vf0, o[nt], 0, 0, 0);
        o[nt] = __builtin_amdgcn_mfma_f32_16x16x32_bf16(pa1, vf1, o[nt], 0, 0, 0);
      }
      __builtin_amdgcn_s_setprio(0);
    }

    if (more) __syncthreads();  // drains DMA (vmcnt0) + publishes buf^1
    cur ^= 1;
  }

  if (!split) {
    // direct write Y: lane holds O[q=4g+r][d=16nt+ln]
    const int bb = head / NH, hh = head - bb * NH;
    __bf16* Yp = Y + ((size_t)bb * S_LEN) * DMODEL + hh * HD;
#pragma unroll
    for (int r = 0; r < 4; ++r) {
      float inv = 1.0f / o5[r];
      int qr = q0 + 4 * g + r;
#pragma unroll
      for (int nt = 0; nt < 4; ++nt)
        Yp[(size_t)qr * DMODEL + 16 * nt + ln] = (__bf16)(o[nt][r] * inv);
    }
  } else {
    // partial slab: O bf16 [128 rows][64 d] + rowsum f32 [128]
    // per-head slab offsets: c8..15(np2)->0..15, c16..23(np3)->16..39,
    // c24..31(np4)->40..71
    int soff;
    if (c < 16) soff = (c - 8) * 2 + part;
    else if (c < 24) soff = 16 + (c - 16) * 3 + part;
    else soff = 40 + (c - 24) * 4 + part;
    char* slab = Po + ((size_t)head * 72 + soff) * SLAB_STRIDE;
#pragma unroll
    for (int r = 0; r < 4; ++r) {
      int rowL = 16 * wv + 4 * g + r;
#pragma unroll
      for (int nt = 0; nt < 4; ++nt)
        *(__bf16*)(slab + (rowL * 64 + 16 * nt + ln) * 2) = (__bf16)o[nt][r];
      if (ln == 0) *(float*)(slab + 16384 + rowL * 4) = o5[r];
    }
  }
}

// ---------------- combine split-chunk partials (sum np slabs; 32 rows/block) ----------------
__global__ __launch_bounds__(256) void attn_combine(const char* __restrict__ Po,
                                                    __bf16* __restrict__ Y) {
  const int blk = blockIdx.x;  // 0..2303 = head * 96 + (chunk-8)*4 + quarter
  const int head = blk / 96, rem = blk - head * 96;
  const int cc = rem >> 2, quarter = rem & 3;
  const int c = cc + 8;
  int np, boff;
  if (c < 16) {
    np = 2;
    boff = (c - 8) * 2;
  } else if (c < 24) {
    np = 3;
    boff = 16 + (c - 16) * 3;
  } else {
    np = 4;
    boff = 40 + (c - 24) * 4;
  }
  const char* s = Po + ((size_t)head * 72 + boff) * SLAB_STRIDE;
  const int tid = threadIdx.x;
  const int row = quarter * 32 + (tid >> 3), d0 = (tid & 7) * 8;

  float acc[8] = {0.f, 0.f, 0.f, 0.f, 0.f, 0.f, 0.f, 0.f};
  float rs = 0.f;
  for (int p = 0; p < np; ++p) {
    bf16x8 a = *(const bf16x8*)(s + (size_t)p * SLAB_STRIDE + (row * 64 + d0) * 2);
#pragma unroll
    for (int j = 0; j < 8; ++j) acc[j] += (float)a[j];
    rs += *(const float*)(s + (size_t)p * SLAB_STRIDE + 16384 + row * 4);
  }
  float inv = 1.0f / rs;

  const int bb = head / NH, hh = head - bb * NH;
  __bf16* yp = Y + ((size_t)bb * S_LEN + 128 * c + row) * DMODEL + hh * HD + d0;
  bf16x8 o;
#pragma unroll
  for (int j = 0; j < 8; ++j) o[j] = (__bf16)(acc[j] * inv);
  *(bf16x8*)yp = o;
}

extern "C" void kernel_launch(void* const* d_in, const int* in_sizes, int n_in,
                              void* d_out, int out_size, void* d_ws, size_t ws_size,
                              hipStream_t stream) {
  const float* x = (const float*)d_in[0];
  const float* Wqkv = (const float*)d_in[1];
  const float* bqkv = (const float*)d_in[2];
  const float* Wout = (const float*)d_in[3];
  const float* bout = (const float*)d_in[4];
  float* out = (float*)d_out;

  char* ws = (char*)d_ws;
  size_t off = 0;
  auto take = [&](size_t bytes) {
    char* p = ws + off;
    off += bytes;
    return p;
  };
  const size_t MD2 = (size_t)MTOT * DMODEL * 2;
  __bf16* xb = (__bf16*)take(MD2);
  __bf16* Wqkv_t = (__bf16*)take((size_t)3 * DMODEL * DMODEL * 2);
  __bf16* Wout_t = (__bf16*)take((size_t)DMODEL * DMODEL * 2);
  __bf16* Qb = (__bf16*)take(MD2);
  __bf16* Kb = (__bf16*)take(MD2);
  __bf16* Vtb = (__bf16*)take(MD2);
  __bf16* Yb = (__bf16*)take(MD2);
  char* Po = take((size_t)24 * 72 * SLAB_STRIDE);  // 24 heads x 72 slabs

  int n8 = MTOT * DMODEL / 8;
  cvt_f32_bf16<<<(n8 + 255) / 256, 256, 0, stream>>>(x, xb, n8);
  transpose_cvt<<<dim3(DMODEL / 64, 3 * DMODEL / 64), 256, 0, stream>>>(Wqkv, Wqkv_t, 3 * DMODEL);
  transpose_cvt<<<dim3(DMODEL / 64, DMODEL / 64), 256, 0, stream>>>(Wout, Wout_t, DMODEL);
  gemm_qkv<<<64 * (3 * DMODEL / 128), 256, 0, stream>>>(xb, Wqkv_t, bqkv, Qb, Kb, Vtb);
  attn_fwd18<<<1920, 512, 0, stream>>>(Qb, Kb, Vtb, Yb, Po);
  attn_combine<<<2304, 256, 0, stream>>>(Po, Yb);
  gemm_out<<<64 * (DMODEL / 128), 256, 0, stream>>>(Yb, Wout_t, bout, out);
}